// Round 2
// baseline (269.780 us; speedup 1.0000x reference)
//
#include <hip/hip_runtime.h>
#include <hip/hip_fp16.h>

#define S_LEN  1000
#define DMODEL 512
#define DHEAD  64
#define NKT    16
#define QSCALE 0.125f

typedef __attribute__((ext_vector_type(8))) short bf16x8;
typedef __attribute__((ext_vector_type(4))) float f32x4;

// LDS layout (64 KB static):
//  OFF_KS  [64][64]  bf16 K*scale   (P tile overlays it after softmax)
//  OFF_RKS [128][64] bf16 RkE rows  (W tile [64][128] overlays it after softmax)
//  OFF_VT  [64][64]  bf16 V transposed  [d][k]
//  OFF_RVT [64][128] bf16 RvE transposed [d][delta]
//  OFF_S2T [128][64] f16  bias S2 transposed [delta][q]
#define OFF_KS   0u
#define OFF_RKS  8192u
#define OFF_VT   24576u
#define OFF_RVT  32768u
#define OFF_S2T  49152u

static __device__ __forceinline__ unsigned short f2bf(float x){
  union{float f; unsigned u;} v; v.f = x;
  return (unsigned short)((v.u + 0x7FFFu + ((v.u>>16)&1u)) >> 16);
}
static __device__ __forceinline__ float bf2f(unsigned short h){
  union{unsigned u; float f;} v; v.u = ((unsigned)h)<<16; return v.f;
}
static __device__ __forceinline__ int cidx(int g){
  int r = g % S_LEN; if (r < 0) r += S_LEN;
  int r2 = S_LEN - r;
  return r < r2 ? r : r2;
}

#define F4LD(dst, ptr, i) { float4 _t = reinterpret_cast<const float4*>(ptr)[i]; \
  (dst)[4*(i)]=_t.x; (dst)[4*(i)+1]=_t.y; (dst)[4*(i)+2]=_t.z; (dst)[4*(i)+3]=_t.w; }

__global__ __launch_bounds__(256, 2)
void cra_attn(const float* __restrict__ Qg, const float* __restrict__ Kg,
              const float* __restrict__ Vg, const float* __restrict__ RKg,
              const float* __restrict__ RVg, float* __restrict__ Og)
{
  __shared__ char sm[65536];

  const int tid  = threadIdx.x;
  const int lane = tid & 63;
  const int w    = tid >> 6;     // wave 0..3 -> q-strip rows [16w,16w+16)
  const int lo   = lane & 15;
  const int hi   = lane >> 4;

  const int bid = blockIdx.x;
  const int qt  = bid & 15;
  const int h   = (bid >> 4) & 7;
  const int b   = bid >> 7;
  const int q0  = qt * 64;

  const int rowA = w*16 + lo;                       // A-fragment row (q, block-local)
  const unsigned swzA7  = (((unsigned)rowA)&7u)<<4;
  const unsigned swzA15 = (((unsigned)rowA)&15u)<<4;

  // ---- Q fragments straight from global (per-lane fixed rows), split hi/lo bf16 ----
  bf16x8 aq[2], aql[2];
  {
    int qr = q0 + rowA; if (qr > S_LEN-1) qr = S_LEN-1;
    const float* qsrc = Qg + ((size_t)b*S_LEN + qr)*DMODEL + h*DHEAD;
#pragma unroll
    for (int kk=0;kk<2;kk++){
      float v[8];
      F4LD(v, qsrc + hi*8 + 32*kk, 0);
      F4LD(v, qsrc + hi*8 + 32*kk, 1);
      union{ bf16x8 f; unsigned short s[8]; } th, tl;
#pragma unroll
      for (int j=0;j<8;j++){
        unsigned short hb = f2bf(v[j]);
        th.s[j] = hb;
        tl.s[j] = f2bf(v[j] - bf2f(hb));
      }
      aq[kk]  = th.f;
      aql[kk] = tl.f;
    }
  }

  f32x4 acc[4];
  float m_run[4], l_run[4];
#pragma unroll
  for (int i=0;i<4;i++){
    acc[i] = (f32x4){0.f,0.f,0.f,0.f};
    m_run[i] = -1e30f; l_run[i] = 0.f;
  }

  for (int kt=0; kt<NKT; ++kt){
    const int k0 = kt*64;
    __syncthreads();   // S0: prior-iteration LDS reads complete before restaging

    // ---- stage K (scale folded) and V-transposed ----
    {
      const int kb = tid >> 2;
      const int d0 = (tid & 3)*16;
      int kr = k0 + kb; if (kr > S_LEN-1) kr = S_LEN-1;
      const float* srck = Kg + ((size_t)b*S_LEN + kr)*DMODEL + h*DHEAD + d0;
      const float* srcv = Vg + ((size_t)b*S_LEN + kr)*DMODEL + h*DHEAD + d0;
      float vk[16], vv[16];
#pragma unroll
      for (int i=0;i<4;i++){ F4LD(vk, srck, i); F4LD(vv, srcv, i); }
#pragma unroll
      for (int c=0;c<2;c++){
        union{ uint4 q; unsigned short s[8]; } t;
#pragma unroll
        for (int i=0;i<8;i++) t.s[i] = f2bf(vk[8*c+i]*QSCALE);
        *(uint4*)(sm + OFF_KS + (((unsigned)(kb*128 + d0*2 + 16*c)) ^ ((((unsigned)kb)&7u)<<4))) = t.q;
      }
#pragma unroll
      for (int i=0;i<16;i++){
        const int d = d0+i;
        *(unsigned short*)(sm + OFF_VT + (((unsigned)(d*128 + kb*2)) ^ ((((unsigned)d)&7u)<<4))) = f2bf(vv[i]);
      }
    }
    // ---- stage RkE window [q0-k0-63 .. +64] and RvE-transposed ----
    {
      const int di = tid >> 1;            // 0..127
      const int d0 = (tid & 1)*32;
      const int row = cidx(q0 - k0 - 63 + di);
      const float* srk = RKg + (size_t)row*DHEAD + d0;
      const float* srv = RVg + (size_t)row*DHEAD + d0;
      float vk[32], vv[32];
#pragma unroll
      for (int i=0;i<8;i++){ F4LD(vk, srk, i); F4LD(vv, srv, i); }
#pragma unroll
      for (int c=0;c<4;c++){
        union{ uint4 q; unsigned short s[8]; } t;
#pragma unroll
        for (int i=0;i<8;i++) t.s[i] = f2bf(vk[8*c+i]);
        *(uint4*)(sm + OFF_RKS + (((unsigned)(di*128 + d0*2 + 16*c)) ^ ((((unsigned)di)&7u)<<4))) = t.q;
      }
#pragma unroll
      for (int i=0;i<32;i++){
        const int d = d0+i;
        *(unsigned short*)(sm + OFF_RVT + (((unsigned)(d*256 + di*2)) ^ ((((unsigned)d)&15u)<<4))) = f2bf(vv[i]);
      }
    }
    __syncthreads();   // S2: tiles staged

    // ---- C1: S1 = Q Kt (scaled), per-wave 16x64 strip ----
    f32x4 sf[4];
#pragma unroll
    for (int fc=0;fc<4;fc++){
      sf[fc] = (f32x4){0.f,0.f,0.f,0.f};
#pragma unroll
      for (int kk=0;kk<2;kk++){
        const int rb = fc*16+lo;
        bf16x8 bk = *(const bf16x8*)(sm + OFF_KS + (((unsigned)(rb*128 + hi*16 + 64*kk)) ^ ((((unsigned)rb)&7u)<<4)));
        sf[fc] = __builtin_amdgcn_mfma_f32_16x16x32_bf16(aq[kk], bk, sf[fc], 0,0,0);
      }
    }
    // ---- S2 = (Qhi+Qlo) RkEt, 16x128 strip, stored transposed as f16 ----
#pragma unroll
    for (int dc=0;dc<8;dc++){
      const int dr = dc*16+lo;
      f32x4 s2 = (f32x4){0.f,0.f,0.f,0.f};
#pragma unroll
      for (int kk=0;kk<2;kk++){
        bf16x8 br = *(const bf16x8*)(sm + OFF_RKS + (((unsigned)(dr*128 + hi*16 + 64*kk)) ^ ((((unsigned)dr)&7u)<<4)));
        s2 = __builtin_amdgcn_mfma_f32_16x16x32_bf16(aq[kk],  br, s2, 0,0,0);
        s2 = __builtin_amdgcn_mfma_f32_16x16x32_bf16(aql[kk], br, s2, 0,0,0);
      }
      union{ unsigned long long q; unsigned short s[4]; } t;
#pragma unroll
      for (int r=0;r<4;r++) t.s[r] = __half_as_ushort(__float2half(s2[r]));
      *(unsigned long long*)(sm + OFF_S2T +
          (((unsigned)(dr*128 + (w*16+hi*4)*2)) ^ ((((unsigned)dr)&7u)<<4))) = t.q;
    }
    __syncthreads();   // S2b: S2T stores visible before bias reads (compiler + HW fence)

    // ---- C2: online softmax (fp32, wave-local) ----
    float p[4][4], rsc[4];
#pragma unroll
    for (int r=0;r<4;r++){
      const int rowB = w*16 + hi*4 + r;
      float scv[4];
      float mx = -1e30f;
#pragma unroll
      for (int fc=0;fc<4;fc++){
        const int kB = fc*16 + lo;
        const int dg = rowB - kB + 63;     // delta index in the staged window
        unsigned short hb = *(const unsigned short*)(sm + OFF_S2T +
            (((unsigned)(dg*128 + rowB*2)) ^ ((((unsigned)dg)&7u)<<4)));
        float vv2 = sf[fc][r] + __half2float(__ushort_as_half(hb));
        if (k0 + kB >= S_LEN) vv2 = -1e30f;
        scv[fc] = vv2;
        mx = fmaxf(mx, vv2);
      }
      mx = fmaxf(mx, __shfl_xor(mx,1));
      mx = fmaxf(mx, __shfl_xor(mx,2));
      mx = fmaxf(mx, __shfl_xor(mx,4));
      mx = fmaxf(mx, __shfl_xor(mx,8));
      const float mnew = fmaxf(m_run[r], mx);
      const float rr = __expf(m_run[r] - mnew);
      m_run[r] = mnew; rsc[r] = rr;
      float sum = 0.f;
#pragma unroll
      for (int fc=0;fc<4;fc++){
        const float pv = __expf(scv[fc] - mnew);
        p[fc][r] = pv; sum += pv;
      }
      sum += __shfl_xor(sum,1);
      sum += __shfl_xor(sum,2);
      sum += __shfl_xor(sum,4);
      sum += __shfl_xor(sum,8);
      l_run[r] = l_run[r]*rr + sum;
    }
#pragma unroll
    for (int fc=0;fc<4;fc++){
#pragma unroll
      for (int r=0;r<4;r++) acc[fc][r] *= rsc[r];
    }

    __syncthreads();   // S3: all waves done reading Ks/Rks/S2T -> safe to overlay P/W

    // ---- C3: zero W strip (linear), then scatter W[q][delta]=p and P[q][k]=p ----
    {
      const uint4 z = {0u,0u,0u,0u};
#pragma unroll
      for (int c=0;c<4;c++)
        *(uint4*)(sm + OFF_RKS + (unsigned)((w*16+lo)*256 + hi*16 + c*64)) = z;
    }
    asm volatile("" ::: "memory");   // order zero-fill before scatter (TBAA says they don't alias)
#pragma unroll
    for (int r=0;r<4;r++){
      const int rowB = w*16 + hi*4 + r;
#pragma unroll
      for (int fc=0;fc<4;fc++){
        const int kB = fc*16 + lo;
        const int dg = rowB - kB + 63;
        const unsigned short pb = f2bf(p[fc][r]);
        *(unsigned short*)(sm + OFF_RKS + (((unsigned)(rowB*256 + dg*2)) ^ ((((unsigned)rowB)&15u)<<4))) = pb;
        *(unsigned short*)(sm + OFF_KS  + (((unsigned)(rowB*128 + kB*2)) ^ ((((unsigned)rowB)&7u)<<4)))  = pb;
      }
    }
    __syncthreads();   // S3b: P/W scatter visible before MFMA A-fragment reads

    // ---- C4: acc += P @ Vt  +  W @ RvEt ----
    bf16x8 ap[2];
#pragma unroll
    for (int kk=0;kk<2;kk++)
      ap[kk] = *(const bf16x8*)(sm + OFF_KS + (((unsigned)(rowA*128 + hi*16 + 64*kk)) ^ swzA7));
#pragma unroll
    for (int kk=0;kk<2;kk++){
#pragma unroll
      for (int fc=0;fc<4;fc++){
        const int rb = fc*16+lo;
        bf16x8 bv = *(const bf16x8*)(sm + OFF_VT + (((unsigned)(rb*128 + hi*16 + 64*kk)) ^ ((((unsigned)rb)&7u)<<4)));
        acc[fc] = __builtin_amdgcn_mfma_f32_16x16x32_bf16(ap[kk], bv, acc[fc], 0,0,0);
      }
    }
#pragma unroll
    for (int kk=0;kk<4;kk++){
      bf16x8 aw = *(const bf16x8*)(sm + OFF_RKS + (((unsigned)(rowA*256 + hi*16 + 64*kk)) ^ swzA15));
#pragma unroll
      for (int fc=0;fc<4;fc++){
        const int rb = fc*16+lo;
        bf16x8 bw = *(const bf16x8*)(sm + OFF_RVT + (((unsigned)(rb*256 + hi*16 + 64*kk)) ^ ((((unsigned)rb)&15u)<<4)));
        acc[fc] = __builtin_amdgcn_mfma_f32_16x16x32_bf16(aw, bw, acc[fc], 0,0,0);
      }
    }
  }

  // ---- epilogue: normalize and store ----
#pragma unroll
  for (int fc=0;fc<4;fc++){
#pragma unroll
    for (int r=0;r<4;r++){
      const int rowB = w*16 + hi*4 + r;
      const int q = q0 + rowB;
      if (q < S_LEN)
        Og[((size_t)b*S_LEN + q)*DMODEL + h*DHEAD + fc*16 + lo] = acc[fc][r] / l_run[r];
    }
  }
}

extern "C" void kernel_launch(void* const* d_in, const int* in_sizes, int n_in,
                              void* d_out, int out_size, void* d_ws, size_t ws_size,
                              hipStream_t stream) {
  (void)in_sizes; (void)n_in; (void)out_size; (void)d_ws; (void)ws_size;
  const float* Q  = (const float*)d_in[0];
  const float* K  = (const float*)d_in[1];
  const float* V  = (const float*)d_in[2];
  const float* RK = (const float*)d_in[3];
  const float* RV = (const float*)d_in[4];
  float* O = (float*)d_out;
  cra_attn<<<dim3(8*8*16), dim3(256), 0, stream>>>(Q, K, V, RK, RV, O);
}

// Round 3
// 259.136 us; speedup vs baseline: 1.0411x; 1.0411x over previous
//
#include <hip/hip_runtime.h>
#include <hip/hip_fp16.h>

#define S_LEN  1000
#define NH     8
#define DH     64
#define NKT    16
#define QSCALE 0.125f

typedef __attribute__((ext_vector_type(8))) _Float16 f16x8;
typedef __attribute__((ext_vector_type(4))) float    f32x4;

// ---- workspace layout (16 MB total) ----
// VTh: f16 [64 bh][64 d][1024 k]   (k>=1000 zero-padded)    8 MB @ 0
// RKW: f16 [256 win][128 dl][64 d]                          4 MB @ 8 MB
// RVW: f16 [256 win][64 d][128 dl]                          4 MB @ 12 MB
#define WS_VTH 0ull
#define WS_RKW (8ull*1024*1024)
#define WS_RVW (12ull*1024*1024)

// ---- LDS layout (48 KB) ----
//  OFF_KS  [64 k][128B]  f16 K*scale  (P[q][k] overlays after softmax)
//  OFF_VT  [64 d][128B]  f16 V^T
//  OFF_RVT [64 d][256B]  f16 RvE^T window
//  OFF_SW  [4 w][4KB]    per-wave: S2T [128 dg][16 q] f16, then W [16 q][128 dg] f16
#define OFF_KS   0u
#define OFF_VT   8192u
#define OFF_RVT  16384u
#define OFF_SW   32768u

static __device__ __forceinline__ int cidx(int g){
  int r = g % S_LEN; if (r < 0) r += S_LEN;
  int r2 = S_LEN - r;
  return r < r2 ? r : r2;
}

#define F4LD(dst, ptr, i) { float4 _t = reinterpret_cast<const float4*>(ptr)[i]; \
  (dst)[4*(i)]=_t.x; (dst)[4*(i)+1]=_t.y; (dst)[4*(i)+2]=_t.z; (dst)[4*(i)+3]=_t.w; }

// ============ prologue 1: V -> VTh f16 [bh][d][k], zero-padded to k=1024 ============
__global__ __launch_bounds__(256)
void p_vt(const float* __restrict__ Vg, _Float16* __restrict__ VTh)
{
  __shared__ float tile[64][65];
  const int blk = blockIdx.x;
  const int bh  = blk >> 4;
  const int k0  = (blk & 15) * 64;
  const int b = bh >> 3, h = bh & 7;
  const int t = threadIdx.x;
  {
    const int kb = t >> 2, dq = (t & 3) * 16;
    const int k = k0 + kb;
    float v[16];
    if (k < S_LEN) {
      const float* src = Vg + ((size_t)(b*S_LEN + k))*512 + h*DH + dq;
#pragma unroll
      for (int i=0;i<4;i++) F4LD(v, src, i);
    } else {
#pragma unroll
      for (int i=0;i<16;i++) v[i] = 0.f;
    }
#pragma unroll
    for (int i=0;i<16;i++) tile[kb][dq+i] = v[i];
  }
  __syncthreads();
  {
    const int d = t >> 2, kq = (t & 3) * 16;
    union { uint4 q[2]; _Float16 h[16]; } o;
#pragma unroll
    for (int i=0;i<16;i++) o.h[i] = (_Float16)tile[kq+i][d];
    _Float16* dst = VTh + ((size_t)(bh*64 + d))*1024 + k0 + kq;
    reinterpret_cast<uint4*>(dst)[0] = o.q[0];
    reinterpret_cast<uint4*>(dst)[1] = o.q[1];
  }
}

// ============ prologue 2: gather circular windows into RKW / RVW ============
__global__ __launch_bounds__(256)
void p_rel(const float* __restrict__ RKg, const float* __restrict__ RVg,
           _Float16* __restrict__ RKW, _Float16* __restrict__ RVW)
{
  const int win = blockIdx.x;            // qt*16 + kt
  const int qt = win >> 4, kt = win & 15;
  const int base = qt*64 - kt*64 - 63;
  const int t = threadIdx.x;
  const int dl = t >> 1;                 // delta 0..127
  const int dh = (t & 1) * 32;
  const int row = cidx(base + dl);
  float vk[32], vv[32];
  const float* sk = RKg + (size_t)row*DH + dh;
  const float* sv = RVg + (size_t)row*DH + dh;
#pragma unroll
  for (int i=0;i<8;i++){ F4LD(vk, sk, i); F4LD(vv, sv, i); }
  {
    union { uint4 q[4]; _Float16 h[32]; } o;
#pragma unroll
    for (int i=0;i<32;i++) o.h[i] = (_Float16)vk[i];
    _Float16* dst = RKW + (size_t)win*8192 + dl*64 + dh;
#pragma unroll
    for (int c=0;c<4;c++) reinterpret_cast<uint4*>(dst)[c] = o.q[c];
  }
  {
    _Float16* dst = RVW + (size_t)win*8192 + dl;
#pragma unroll
    for (int i=0;i<32;i++) dst[(size_t)(dh+i)*128] = (_Float16)vv[i];
  }
}

// ============ main fused attention ============
__global__ __launch_bounds__(256, 3)
void cra_attn(const float* __restrict__ Qg, const float* __restrict__ Kg,
              const _Float16* __restrict__ VTh, const _Float16* __restrict__ RKW,
              const _Float16* __restrict__ RVW, float* __restrict__ Og)
{
  __shared__ char sm[49152];

  const int tid  = threadIdx.x;
  const int lane = tid & 63;
  const int w    = tid >> 6;
  const int lo   = lane & 15;
  const int hi   = lane >> 4;

  // XCD-aware bijective swizzle (1024 % 8 == 0)
  const int bid = (blockIdx.x & 7) * 128 + (blockIdx.x >> 3);
  const int qt  = bid & 15;
  const int h   = (bid >> 4) & 7;
  const int b   = bid >> 7;
  const int bh  = b*NH + h;
  const int q0  = qt * 64;

  const int rowA = w*16 + lo;

  // ---- Q fragments from global, f16 ----
  f16x8 aq[2];
  {
    int qr = q0 + rowA; if (qr > S_LEN-1) qr = S_LEN-1;
    const float* qsrc = Qg + ((size_t)b*S_LEN + qr)*512 + h*DH;
#pragma unroll
    for (int kk=0;kk<2;kk++){
      float v[8];
      F4LD(v, qsrc + hi*8 + 32*kk, 0);
      F4LD(v, qsrc + hi*8 + 32*kk, 1);
      union { f16x8 f; _Float16 h[8]; } c;
#pragma unroll
      for (int j=0;j<8;j++) c.h[j] = (_Float16)v[j];
      aq[kk] = c.f;
    }
  }

  f32x4 acc[4];
  float m_run[4], l_run[4];
#pragma unroll
  for (int i=0;i<4;i++){
    acc[i] = (f32x4){0.f,0.f,0.f,0.f};
    m_run[i] = -1e30f; l_run[i] = 0.f;
  }

  for (int kt=0; kt<NKT; ++kt){
    const int k0 = kt*64;
    const int win = qt*16 + kt;
    __syncthreads();   // S0: prior-iter LDS reads complete before restage

    // ---- stage Ks (f32 K -> f16*scale), vectorized ----
    {
      const int kb = tid >> 2;
      const int d0 = (tid & 3)*16;
      int kr = k0 + kb; if (kr > S_LEN-1) kr = S_LEN-1;
      const float* srck = Kg + ((size_t)b*S_LEN + kr)*512 + h*DH + d0;
      float vk[16];
#pragma unroll
      for (int i=0;i<4;i++) F4LD(vk, srck, i);
      union { uint4 q[2]; _Float16 h[16]; } o;
#pragma unroll
      for (int i=0;i<16;i++) o.h[i] = (_Float16)(vk[i]*QSCALE);
#pragma unroll
      for (int c=0;c<2;c++)
        *(uint4*)(sm + OFF_KS + (((unsigned)(kb*128 + d0*2 + 16*c)) ^ ((((unsigned)kb)&7u)<<4))) = o.q[c];
    }
    // ---- stage Vt from VTh (pure f16 copy) ----
    {
      const int d = tid >> 2;
      const int kq4 = tid & 3;
      const _Float16* src = VTh + ((size_t)(bh*64 + d))*1024 + k0 + kq4*16;
      uint4 q0v = reinterpret_cast<const uint4*>(src)[0];
      uint4 q1v = reinterpret_cast<const uint4*>(src)[1];
      *(uint4*)(sm + OFF_VT + (((unsigned)(d*128 + kq4*32))      ^ ((((unsigned)d)&7u)<<4))) = q0v;
      *(uint4*)(sm + OFF_VT + (((unsigned)(d*128 + kq4*32 + 16)) ^ ((((unsigned)d)&7u)<<4))) = q1v;
    }
    // ---- stage RvT from RVW (pure f16 copy) ----
    {
      const int d = tid >> 2;
      const int dc4 = tid & 3;
      const _Float16* src = RVW + (size_t)win*8192 + d*128 + dc4*32;
#pragma unroll
      for (int c=0;c<4;c++){
        uint4 qv = reinterpret_cast<const uint4*>(src)[c];
        *(uint4*)(sm + OFF_RVT + (((unsigned)(d*256 + dc4*64 + 16*c)) ^ ((((unsigned)d)&15u)<<4))) = qv;
      }
    }
    __syncthreads();   // S2: tiles staged

    // ---- C1: S1 = Q (K*scale)^T ----
    f32x4 sf[4];
#pragma unroll
    for (int fc=0;fc<4;fc++){
      sf[fc] = (f32x4){0.f,0.f,0.f,0.f};
#pragma unroll
      for (int kk=0;kk<2;kk++){
        const int rb = fc*16+lo;
        f16x8 bk = *(const f16x8*)(sm + OFF_KS + (((unsigned)(rb*128 + hi*16 + 64*kk)) ^ ((((unsigned)rb)&7u)<<4)));
        sf[fc] = __builtin_amdgcn_mfma_f32_16x16x32_f16(aq[kk], bk, sf[fc], 0,0,0);
      }
    }
    // ---- S2 = Q RkE^T, B-fragments straight from global RKW; store wave-private S2T ----
    {
      const _Float16* rkw = RKW + (size_t)win*8192;
      const int lane_off = lo*64 + hi*8;
#pragma unroll
      for (int dc=0;dc<8;dc++){
        f32x4 s2 = (f32x4){0.f,0.f,0.f,0.f};
#pragma unroll
        for (int kk=0;kk<2;kk++){
          f16x8 br = *(const f16x8*)(rkw + (dc*16)*64 + lane_off + kk*32);
          s2 = __builtin_amdgcn_mfma_f32_16x16x32_f16(aq[kk], br, s2, 0,0,0);
        }
        const int dr = dc*16 + lo;
        union { unsigned long long u; _Float16 h[4]; } t;
#pragma unroll
        for (int r=0;r<4;r++) t.h[r] = (_Float16)s2[r];
        *(unsigned long long*)(sm + OFF_SW + (unsigned)(w*4096 + dr*32 + ((hi*8) ^ ((dr&3)<<3)))) = t.u;
      }
    }
    asm volatile("" ::: "memory");   // order S2T stores before bias reads (same wave, DS in-order)

    // ---- C2: online softmax (fp32) ----
    float p[4][4], rsc[4];
#pragma unroll
    for (int r=0;r<4;r++){
      const int rowB = w*16 + hi*4 + r;
      const int q16  = hi*4 + r;
      float scv[4];
      float mx = -1e30f;
#pragma unroll
      for (int fc=0;fc<4;fc++){
        const int kB = fc*16 + lo;
        const int dg = rowB - kB + 63;
        const _Float16 hb = *(const _Float16*)(sm + OFF_SW +
            (unsigned)(w*4096 + dg*32 + ((((q16>>2) ^ (dg&3))<<3) + (q16&3)*2)));
        float vv2 = sf[fc][r] + (float)hb;
        if (k0 + kB >= S_LEN) vv2 = -1e30f;
        scv[fc] = vv2;
        mx = fmaxf(mx, vv2);
      }
      mx = fmaxf(mx, __shfl_xor(mx,1));
      mx = fmaxf(mx, __shfl_xor(mx,2));
      mx = fmaxf(mx, __shfl_xor(mx,4));
      mx = fmaxf(mx, __shfl_xor(mx,8));
      const float mnew = fmaxf(m_run[r], mx);
      const float rr = __expf(m_run[r] - mnew);
      m_run[r] = mnew; rsc[r] = rr;
      float sum = 0.f;
#pragma unroll
      for (int fc=0;fc<4;fc++){
        const float pv = __expf(scv[fc] - mnew);
        p[fc][r] = pv; sum += pv;
      }
      sum += __shfl_xor(sum,1);
      sum += __shfl_xor(sum,2);
      sum += __shfl_xor(sum,4);
      sum += __shfl_xor(sum,8);
      l_run[r] = l_run[r]*rr + sum;
    }
#pragma unroll
    for (int fc=0;fc<4;fc++){
#pragma unroll
      for (int r=0;r<4;r++) acc[fc][r] *= rsc[r];
    }
    asm volatile("" ::: "memory");   // all S2T reads done before W zero-fill (same region)

    // ---- W zero-fill (wave-private region overlaying S2T) ----
    {
      const uint4 z = {0u,0u,0u,0u};
#pragma unroll
      for (int c=0;c<4;c++)
        *(uint4*)(sm + OFF_SW + (unsigned)(w*4096 + lo*256 + ((hi*64 + c*16) ^ ((lo&15)<<4)))) = z;
    }
    asm volatile("" ::: "memory");

    __syncthreads();   // S3: all waves done reading Ks as K -> safe to overlay P

    // ---- scatter P[q][k] (Ks region) and W[q][dg] (wave region) ----
#pragma unroll
    for (int r=0;r<4;r++){
      const int rowB = w*16 + hi*4 + r;
      const int q16  = hi*4 + r;
#pragma unroll
      for (int fc=0;fc<4;fc++){
        const int kB = fc*16 + lo;
        const int dg = rowB - kB + 63;
        const _Float16 pb = (_Float16)p[fc][r];
        *(_Float16*)(sm + OFF_KS + (unsigned)(rowB*128 + ((((kB*2)&0x70) ^ ((rowB&7)<<4)) + (kB&7)*2))) = pb;
        *(_Float16*)(sm + OFF_SW + (unsigned)(w*4096 + q16*256 + ((((dg>>3)<<4) ^ ((q16&15)<<4)) + (dg&7)*2))) = pb;
      }
    }
    asm volatile("" ::: "memory");   // scatter before A-fragment reads (same wave)

    // ---- C4: acc += P @ V^T + W @ RvE^T ----
    f16x8 ap[2];
#pragma unroll
    for (int kk=0;kk<2;kk++)
      ap[kk] = *(const f16x8*)(sm + OFF_KS + (((unsigned)(rowA*128 + hi*16 + 64*kk)) ^ ((((unsigned)rowA)&7u)<<4)));
#pragma unroll
    for (int kk=0;kk<2;kk++){
#pragma unroll
      for (int fc=0;fc<4;fc++){
        const int rb = fc*16+lo;
        f16x8 bv = *(const f16x8*)(sm + OFF_VT + (((unsigned)(rb*128 + hi*16 + 64*kk)) ^ ((((unsigned)rb)&7u)<<4)));
        acc[fc] = __builtin_amdgcn_mfma_f32_16x16x32_f16(ap[kk], bv, acc[fc], 0,0,0);
      }
    }
#pragma unroll
    for (int kk=0;kk<4;kk++){
      f16x8 aw = *(const f16x8*)(sm + OFF_SW + (unsigned)(w*4096 + lo*256 + ((kk*64 + hi*16) ^ ((lo&15)<<4))));
#pragma unroll
      for (int fc=0;fc<4;fc++){
        const int rb = fc*16+lo;
        f16x8 bw = *(const f16x8*)(sm + OFF_RVT + (((unsigned)(rb*256 + kk*64 + hi*16)) ^ ((((unsigned)rb)&15u)<<4)));
        acc[fc] = __builtin_amdgcn_mfma_f32_16x16x32_f16(aw, bw, acc[fc], 0,0,0);
      }
    }
  }

  // ---- epilogue ----
#pragma unroll
  for (int fc=0;fc<4;fc++){
#pragma unroll
    for (int r=0;r<4;r++){
      const int rowB = w*16 + hi*4 + r;
      const int q = q0 + rowB;
      if (q < S_LEN)
        Og[((size_t)b*S_LEN + q)*512 + h*DH + fc*16 + lo] = acc[fc][r] / l_run[r];
    }
  }
}

extern "C" void kernel_launch(void* const* d_in, const int* in_sizes, int n_in,
                              void* d_out, int out_size, void* d_ws, size_t ws_size,
                              hipStream_t stream) {
  (void)in_sizes; (void)n_in; (void)out_size; (void)ws_size;
  const float* Q  = (const float*)d_in[0];
  const float* K  = (const float*)d_in[1];
  const float* V  = (const float*)d_in[2];
  const float* RK = (const float*)d_in[3];
  const float* RV = (const float*)d_in[4];
  float* O = (float*)d_out;
  char* ws = (char*)d_ws;
  _Float16* VTh = (_Float16*)(ws + WS_VTH);
  _Float16* RKW = (_Float16*)(ws + WS_RKW);
  _Float16* RVW = (_Float16*)(ws + WS_RVW);

  p_vt <<<dim3(1024), dim3(256), 0, stream>>>(V, VTh);
  p_rel<<<dim3(256),  dim3(256), 0, stream>>>(RK, RV, RKW, RVW);
  cra_attn<<<dim3(1024), dim3(256), 0, stream>>>(Q, K, VTh, RKW, RVW, O);
}

// Round 4
// 223.626 us; speedup vs baseline: 1.2064x; 1.1588x over previous
//
#include <hip/hip_runtime.h>
#include <hip/hip_fp16.h>

#define S_LEN  1000
#define NH     8
#define DH     64
#define NKT    16
#define QSCALE 0.125f

typedef __attribute__((ext_vector_type(8))) _Float16 f16x8;
typedef __attribute__((ext_vector_type(4))) float    f32x4;

// ---- workspace (f16 element offsets), total 16,672,768 B < 16 MiB ----
// Kh  [64 bh][1000 k][64 d]   (K * scale)
// VTh [64 bh][64 d][1000 k]
// RKC [1128 j][64 d]          RkE[cidx(j)]
// RVC [64 d][1128 j]          RvE[cidx(j)] transposed
#define KH_OFF  0ull
#define VT_OFF  4096000ull
#define RKC_OFF 8192000ull
#define RVC_OFF 8264192ull

// ---- LDS: per-wave 5120 B regions, zero block-level sharing ----
//  +0    (3072B): S2T [80 dgl][32B] f16  -> overlaid by W [16 q][192B] f16
//  +3072 (2048B): P   [16 q][128B] f16
#define WAVE_LDS 5120

static __device__ __forceinline__ int cidx(int g){
  int r = g % S_LEN; if (r < 0) r += S_LEN;
  int r2 = S_LEN - r;
  return r < r2 ? r : r2;
}

#define F4LD(dst, ptr, i) { float4 _t = reinterpret_cast<const float4*>(ptr)[i]; \
  (dst)[4*(i)]=_t.x; (dst)[4*(i)+1]=_t.y; (dst)[4*(i)+2]=_t.z; (dst)[4*(i)+3]=_t.w; }

// ============ prologue 1: Kh (scaled f16) + VTh (f16 transpose) ============
__global__ __launch_bounds__(256)
void p_kv(const float* __restrict__ Kg, const float* __restrict__ Vg,
          _Float16* __restrict__ ws)
{
  __shared__ float tile[64][65];
  const int blk = blockIdx.x;
  const int bh  = blk >> 4;
  const int c   = blk & 15;
  const int b = bh >> 3, h = bh & 7;
  const int t = threadIdx.x;
  const int k0 = c*64;
  {
    const int kb = t >> 2, dq = (t & 3)*16;
    const int k = k0 + kb;
    float vv[16];
    if (k < S_LEN) {
      const float* srcv = Vg + ((size_t)(b*S_LEN + k))*512 + h*DH + dq;
      const float* srck = Kg + ((size_t)(b*S_LEN + k))*512 + h*DH + dq;
      float vk[16];
#pragma unroll
      for (int i=0;i<4;i++){ F4LD(vv, srcv, i); F4LD(vk, srck, i); }
      union { uint4 q[2]; _Float16 h[16]; } o;
#pragma unroll
      for (int i=0;i<16;i++) o.h[i] = (_Float16)(vk[i]*QSCALE);
      _Float16* dst = ws + KH_OFF + ((size_t)bh*S_LEN + k)*64 + dq;
      reinterpret_cast<uint4*>(dst)[0] = o.q[0];
      reinterpret_cast<uint4*>(dst)[1] = o.q[1];
    } else {
#pragma unroll
      for (int i=0;i<16;i++) vv[i] = 0.f;
    }
#pragma unroll
    for (int i=0;i<16;i++) tile[kb][dq+i] = vv[i];
  }
  __syncthreads();
  {
    const int d = t >> 2, kq = (t & 3)*16;
    _Float16* dst = ws + VT_OFF + ((size_t)(bh*64 + d))*S_LEN + k0 + kq;
    if (k0 + kq + 15 < S_LEN) {
      union { uint4 q[2]; _Float16 h[16]; } o;
#pragma unroll
      for (int i=0;i<16;i++) o.h[i] = (_Float16)tile[kq+i][d];
      reinterpret_cast<uint4*>(dst)[0] = o.q[0];
      reinterpret_cast<uint4*>(dst)[1] = o.q[1];
    } else {
#pragma unroll
      for (int i=0;i<16;i++)
        if (k0 + kq + i < S_LEN) dst[i] = (_Float16)tile[kq+i][d];
    }
  }
}

// ============ prologue 2: circular tables RKC / RVC ============
__global__ __launch_bounds__(256)
void p_rel(const float* __restrict__ RKg, const float* __restrict__ RVg,
           _Float16* __restrict__ ws)
{
  const int j  = blockIdx.x*64 + (threadIdx.x >> 2);
  const int dq = (threadIdx.x & 3)*16;
  if (j >= 1128) return;
  const int row = cidx(j);
  float vk[16], vv[16];
  const float* sk = RKg + (size_t)row*DH + dq;
  const float* sv = RVg + (size_t)row*DH + dq;
#pragma unroll
  for (int i=0;i<4;i++){ F4LD(vk, sk, i); F4LD(vv, sv, i); }
  {
    union { uint4 q[2]; _Float16 h[16]; } o;
#pragma unroll
    for (int i=0;i<16;i++) o.h[i] = (_Float16)vk[i];
    _Float16* dst = ws + RKC_OFF + (size_t)j*64 + dq;
    reinterpret_cast<uint4*>(dst)[0] = o.q[0];
    reinterpret_cast<uint4*>(dst)[1] = o.q[1];
  }
#pragma unroll
  for (int i=0;i<16;i++)
    ws[RVC_OFF + (size_t)(dq+i)*1128 + j] = (_Float16)vv[i];
}

// ============ main fused attention: barrier-free, wave-independent ============
__global__ __launch_bounds__(256, 4)
void cra_attn(const float* __restrict__ Qg, const _Float16* __restrict__ ws,
              float* __restrict__ Og)
{
  __shared__ char sm[4*WAVE_LDS];

  const int tid  = threadIdx.x;
  const int lane = tid & 63;
  const int w    = tid >> 6;
  const int lo   = lane & 15;
  const int hi   = lane >> 4;
  char* const smw = sm + w*WAVE_LDS;

  // XCD-aware bijective swizzle: XCD x hosts batch b == x
  const int bid = (blockIdx.x & 7) * 128 + (blockIdx.x >> 3);
  const int qt  = bid & 15;
  const int h   = (bid >> 4) & 7;
  const int b   = bid >> 7;
  const int bh  = b*NH + h;
  const int q0  = qt * 64;

  const _Float16* const Kh  = ws + KH_OFF + (size_t)bh*S_LEN*64;
  const _Float16* const VTh = ws + VT_OFF + (size_t)bh*64*S_LEN;
  const _Float16* const RKC = ws + RKC_OFF;
  const _Float16* const RVC = ws + RVC_OFF;

  // ---- Q fragments (f16), per-lane fixed rows ----
  f16x8 aq[2];
  {
    int qr = q0 + w*16 + lo; if (qr > S_LEN-1) qr = S_LEN-1;
    const float* qsrc = Qg + ((size_t)b*S_LEN + qr)*512 + h*DH;
#pragma unroll
    for (int kk=0;kk<2;kk++){
      float v[8];
      F4LD(v, qsrc + hi*8 + 32*kk, 0);
      F4LD(v, qsrc + hi*8 + 32*kk, 1);
      union { f16x8 f; _Float16 h[8]; } c;
#pragma unroll
      for (int j=0;j<8;j++) c.h[j] = (_Float16)v[j];
      aq[kk] = c.f;
    }
  }

  f32x4 acc[4];
  float m_run[4], l_run[4];
#pragma unroll
  for (int i=0;i<4;i++){
    acc[i] = (f32x4){0.f,0.f,0.f,0.f};
    m_run[i] = -1e30f; l_run[i] = 0.f;
  }

  for (int kt=0; kt<NKT; ++kt){
    const int k0 = kt*64;
    int jv = (qt - kt)*64 - 63 + w*16;       // this wave's window base (dg = q-k+63, dgl = dg - w*16)
    jv = ((jv % S_LEN) + S_LEN) % S_LEN;     // cidx periodic -> fold into [0,1000)
    const int sh  = jv & 7;                  // alignment shift for RVC 16B loads
    const int jv8 = jv - sh;

    // ---- C1: S1 = Q (K*scale)^T, B-frags direct from Kh ----
    const _Float16* kp = Kh + (size_t)k0*64;
    f32x4 sf[4];
#pragma unroll
    for (int fc=0;fc<4;fc++){
      sf[fc] = (f32x4){0.f,0.f,0.f,0.f};
#pragma unroll
      for (int kk=0;kk<2;kk++){
        f16x8 bk = *(const f16x8*)(kp + (fc*16+lo)*64 + kk*32 + hi*8);
        sf[fc] = __builtin_amdgcn_mfma_f32_16x16x32_f16(aq[kk], bk, sf[fc], 0,0,0);
      }
    }
    // ---- S2 = Q RkE^T over this wave's 80-wide dgl window; store wave-private S2T ----
    {
      const _Float16* rp = RKC + (size_t)jv*64;
#pragma unroll
      for (int dc=0;dc<5;dc++){
        f32x4 s2 = (f32x4){0.f,0.f,0.f,0.f};
#pragma unroll
        for (int kk=0;kk<2;kk++){
          f16x8 br = *(const f16x8*)(rp + (dc*16+lo)*64 + kk*32 + hi*8);
          s2 = __builtin_amdgcn_mfma_f32_16x16x32_f16(aq[kk], br, s2, 0,0,0);
        }
        const int dgl = dc*16 + lo;
        union { unsigned long long u; _Float16 h[4]; } t;
#pragma unroll
        for (int r=0;r<4;r++) t.h[r] = (_Float16)s2[r];
        *(unsigned long long*)(smw + (unsigned)(dgl*32 + ((hi*8) ^ ((dgl&3)<<3)))) = t.u;
      }
    }
    asm volatile("" ::: "memory");   // S2T stores ordered before bias reads (same wave)

    // ---- C2: online softmax (fp32) ----
    float p[4][4], rsc[4];
#pragma unroll
    for (int r=0;r<4;r++){
      const int q16 = hi*4 + r;
      float scv[4];
      float mx = -1e30f;
#pragma unroll
      for (int fc=0;fc<4;fc++){
        const int kB = fc*16 + lo;
        const int dgl = q16 - kB + 63;
        const _Float16 hb = *(const _Float16*)(smw +
            (unsigned)(dgl*32 + (((q16>>2) ^ (dgl&3))<<3) + (q16&3)*2));
        float vv2 = sf[fc][r] + (float)hb;
        if (k0 + kB >= S_LEN) vv2 = -1e30f;
        scv[fc] = vv2;
        mx = fmaxf(mx, vv2);
      }
      mx = fmaxf(mx, __shfl_xor(mx,1));
      mx = fmaxf(mx, __shfl_xor(mx,2));
      mx = fmaxf(mx, __shfl_xor(mx,4));
      mx = fmaxf(mx, __shfl_xor(mx,8));
      const float mnew = fmaxf(m_run[r], mx);
      const float rr = __expf(m_run[r] - mnew);
      m_run[r] = mnew; rsc[r] = rr;
      float sum = 0.f;
#pragma unroll
      for (int fc=0;fc<4;fc++){
        const float pv = __expf(scv[fc] - mnew);
        p[fc][r] = pv; sum += pv;
      }
      sum += __shfl_xor(sum,1);
      sum += __shfl_xor(sum,2);
      sum += __shfl_xor(sum,4);
      sum += __shfl_xor(sum,8);
      l_run[r] = l_run[r]*rr + sum;
    }
#pragma unroll
    for (int fc=0;fc<4;fc++){
#pragma unroll
      for (int r=0;r<4;r++) acc[fc][r] *= rsc[r];
    }
    asm volatile("" ::: "memory");   // S2T reads done before W zero-fill (overlaid region)

    // ---- W zero-fill (linear covers swizzled cells; [16 q][192B]) ----
    {
      const uint4 z = {0u,0u,0u,0u};
#pragma unroll
      for (int i=0;i<3;i++)
        *(uint4*)(smw + (unsigned)(i*1024 + lane*16)) = z;
    }
    asm volatile("" ::: "memory");

    // ---- scatter P[q][k] and W[q][dgl'] (wave-private, no barrier) ----
#pragma unroll
    for (int r=0;r<4;r++){
      const int q16 = hi*4 + r;
#pragma unroll
      for (int fc=0;fc<4;fc++){
        const int kB  = fc*16 + lo;
        const int dgp = q16 - kB + 63 + sh;          // shifted dgl'
        const _Float16 pb = (_Float16)p[fc][r];
        const unsigned off = (unsigned)(dgp*2);
        *(_Float16*)(smw + (unsigned)(q16*192) + ((off & 0xC0u) | ((off & 63u) ^ (((unsigned)(q16&3))<<4)))) = pb;
        *(_Float16*)(smw + 3072u + (unsigned)(q16*128) + (((unsigned)(kB*2)) ^ ((((unsigned)q16>>1)&7u)<<4))) = pb;
      }
    }
    asm volatile("" ::: "memory");   // scatter ordered before A-frag reads (same wave)

    // ---- C4: acc += P @ V^T + W @ RvE^T (B-frags direct from VTh/RVC) ----
    f16x8 ap[2];
#pragma unroll
    for (int kk=0;kk<2;kk++)
      ap[kk] = *(const f16x8*)(smw + 3072u + (unsigned)(lo*128) +
                (((unsigned)(kk*64 + hi*16)) ^ ((((unsigned)lo>>1)&7u)<<4)));
#pragma unroll
    for (int kk=0;kk<2;kk++){
#pragma unroll
      for (int fc=0;fc<4;fc++){
        f16x8 bv = *(const f16x8*)(VTh + (size_t)(fc*16+lo)*S_LEN + k0 + kk*32 + hi*8);
        acc[fc] = __builtin_amdgcn_mfma_f32_16x16x32_f16(ap[kk], bv, acc[fc], 0,0,0);
      }
    }
    const _Float16* rvp = RVC + jv8;
#pragma unroll
    for (int kk=0;kk<3;kk++){
      const unsigned o = (unsigned)(kk*64 + hi*16);
      f16x8 aw = *(const f16x8*)(smw + (unsigned)(lo*192) +
                  ((o & 0xC0u) | ((o & 63u) ^ (((unsigned)(lo&3))<<4))));
#pragma unroll
      for (int fc=0;fc<4;fc++){
        f16x8 bw = *(const f16x8*)(rvp + (size_t)(fc*16+lo)*1128 + kk*32 + hi*8);
        acc[fc] = __builtin_amdgcn_mfma_f32_16x16x32_f16(aw, bw, acc[fc], 0,0,0);
      }
    }
  }

  // ---- epilogue ----
#pragma unroll
  for (int fc=0;fc<4;fc++){
#pragma unroll
    for (int r=0;r<4;r++){
      const int q = q0 + w*16 + hi*4 + r;
      if (q < S_LEN)
        Og[((size_t)b*S_LEN + q)*512 + h*DH + fc*16 + lo] = acc[fc][r] / l_run[r];
    }
  }
}

extern "C" void kernel_launch(void* const* d_in, const int* in_sizes, int n_in,
                              void* d_out, int out_size, void* d_ws, size_t ws_size,
                              hipStream_t stream) {
  (void)in_sizes; (void)n_in; (void)out_size; (void)ws_size;
  const float* Q  = (const float*)d_in[0];
  const float* K  = (const float*)d_in[1];
  const float* V  = (const float*)d_in[2];
  const float* RK = (const float*)d_in[3];
  const float* RV = (const float*)d_in[4];
  float* O = (float*)d_out;
  _Float16* ws = (_Float16*)d_ws;

  p_kv <<<dim3(1024), dim3(256), 0, stream>>>(K, V, ws);
  p_rel<<<dim3(18),   dim3(256), 0, stream>>>(RK, RV, ws);
  cra_attn<<<dim3(1024), dim3(256), 0, stream>>>(Q, ws, O);
}